// Round 2
// baseline (196.698 us; speedup 1.0000x reference)
//
#include <hip/hip_runtime.h>

#define B_ 64
#define I_ 1152
#define C_ 32
#define E_ 16
#define D_ 8
#define BC_ 8                    // batch rows per block (4 waves x j=2)
#define WROW_ (C_*D_*E_/4)       // 1024 float4 per W[i]

// Pass kernel: recompute u_hat[b,i,c,e] = sum_d x[b,i,d]*W[i,c,d,e], coupling
// coef (uniform or softmax_c of u_hat . vacc), accumulate partial s over the
// block's i-chunk. Thread map (256 thr): c=t&31, eh=(t>>5)&1 (e-half), bq=t>>6,
// j=0..1 -> b = b0 + bq*2 + j. ICt i's per block, W double-staged via regs (T14).
template<int ICt, bool ROUTE>
__global__ __launch_bounds__(256)
void caps_pass(const float* __restrict__ x, const float* __restrict__ W,
               const float* __restrict__ vacc, float* __restrict__ partial)
{
  __shared__ float4 Wl[C_*32];        // one W[i], quad rotated by c row (16KB)
  __shared__ float4 xl[BC_*ICt*2];    // x for 8 b's x ICt i's

  const int t  = threadIdx.x;
  const int c  = t & 31;
  const int eh = (t >> 5) & 1;
  const int bq = t >> 6;
  const int i0 = blockIdx.x * ICt;
  const int b0 = blockIdx.y * BC_;

  float acc[2][8];
#pragma unroll
  for (int j = 0; j < 2; ++j)
#pragma unroll
    for (int e = 0; e < 8; ++e) acc[j][e] = 0.f;

  float vr[2][8];
  if (ROUTE) {
#pragma unroll
    for (int j = 0; j < 2; ++j) {
      const float4* vp = (const float4*)(vacc + (((size_t)(b0 + bq*2 + j)*C_ + c)*E_ + eh*8));
      float4 a = vp[0], b = vp[1];
      vr[j][0]=a.x; vr[j][1]=a.y; vr[j][2]=a.z; vr[j][3]=a.w;
      vr[j][4]=b.x; vr[j][5]=b.y; vr[j][6]=b.z; vr[j][7]=b.w;
    }
  }

  // stage x for all ICt i's up front: per b, 2*ICt consecutive float4
  for (int f = t; f < BC_*ICt*2; f += 256) {
    int b = f / (ICt*2), r = f % (ICt*2);
    xl[f] = ((const float4*)x)[ ((size_t)(b0 + b)*I_ + i0)*2 + r ];
  }

  // prologue: W[i0] into regs
  const float4* wg = (const float4*)(W + (size_t)i0 * (C_*D_*E_));
  float4 wr[4];
#pragma unroll
  for (int k = 0; k < 4; ++k) wr[k] = wg[t + 256*k];

  for (int ii = 0; ii < ICt; ++ii) {
    __syncthreads();                          // prior LDS reads done (and xl ready at ii=0)
#pragma unroll
    for (int k = 0; k < 4; ++k) {             // write staged W, swizzled
      int f = t + 256*k, cc = f >> 5, q = f & 31;
      Wl[cc*32 + ((q + cc) & 31)] = wr[k];
    }
    if (ii + 1 < ICt) {                       // issue next-i loads; land under compute
      const float4* wn = wg + (size_t)(ii + 1) * WROW_;
#pragma unroll
      for (int k = 0; k < 4; ++k) wr[k] = wn[t + 256*k];
    }
    __syncthreads();

    float xv[2][8];
#pragma unroll
    for (int j = 0; j < 2; ++j) {
      float4 a = xl[(bq*2 + j)*(ICt*2) + ii*2 + 0];
      float4 b = xl[(bq*2 + j)*(ICt*2) + ii*2 + 1];
      xv[j][0]=a.x; xv[j][1]=a.y; xv[j][2]=a.z; xv[j][3]=a.w;
      xv[j][4]=b.x; xv[j][5]=b.y; xv[j][6]=b.z; xv[j][7]=b.w;
    }

    float uh[2][8];
#pragma unroll
    for (int j = 0; j < 2; ++j)
#pragma unroll
      for (int e = 0; e < 8; ++e) uh[j][e] = 0.f;

#pragma unroll
    for (int d = 0; d < D_; ++d) {
#pragma unroll
      for (int qq = 0; qq < 2; ++qq) {
        float4 wv = Wl[c*32 + (((d*4 + eh*2 + qq) + c) & 31)];
        const int eb = qq*4;
#pragma unroll
        for (int j = 0; j < 2; ++j) {
          uh[j][eb+0] = fmaf(xv[j][d], wv.x, uh[j][eb+0]);
          uh[j][eb+1] = fmaf(xv[j][d], wv.y, uh[j][eb+1]);
          uh[j][eb+2] = fmaf(xv[j][d], wv.z, uh[j][eb+2]);
          uh[j][eb+3] = fmaf(xv[j][d], wv.w, uh[j][eb+3]);
        }
      }
    }

    float coef[2];
    if (ROUTE) {
#pragma unroll
      for (int j = 0; j < 2; ++j) {
        float lg = 0.f;
#pragma unroll
        for (int e = 0; e < 8; ++e) lg = fmaf(uh[j][e], vr[j][e], lg);
        lg += __shfl_xor(lg, 32, 64);         // combine e-halves
        float m = lg;
#pragma unroll
        for (int mk = 16; mk >= 1; mk >>= 1) m = fmaxf(m, __shfl_xor(m, mk, 64));
        float p = __expf(lg - m);
        float s = p;
#pragma unroll
        for (int mk = 16; mk >= 1; mk >>= 1) s += __shfl_xor(s, mk, 64);
        coef[j] = p * __builtin_amdgcn_rcpf(s);
      }
    } else {
#pragma unroll
      for (int j = 0; j < 2; ++j) coef[j] = (1.0f / C_);
    }

#pragma unroll
    for (int j = 0; j < 2; ++j)
#pragma unroll
      for (int e = 0; e < 8; ++e) acc[j][e] = fmaf(coef[j], uh[j][e], acc[j][e]);
  }

  // partial s for this i-chunk: [NIC][B][C][E]
#pragma unroll
  for (int j = 0; j < 2; ++j) {
    size_t base = ((size_t)blockIdx.x * B_ + (b0 + bq*2 + j)) * (C_*E_) + (size_t)c*E_ + eh*8;
    float4 o0 = {acc[j][0],acc[j][1],acc[j][2],acc[j][3]};
    float4 o1 = {acc[j][4],acc[j][5],acc[j][6],acc[j][7]};
    *(float4*)(partial + base)     = o0;
    *(float4*)(partial + base + 4) = o1;
  }
}

// Sum partials over NICT chunks -> s[b,c,e]; squash over e (16-lane groups).
// mode 0: vacc_out = v ; mode 1: vacc_out = vacc_in + v ; mode 2: vout = v
template<int NICT>
__global__ __launch_bounds__(256)
void reduce_squash(const float* __restrict__ partial,
                   const float* __restrict__ vacc_in, float* __restrict__ vacc_out,
                   float* __restrict__ vout, int mode)
{
  const int idx = blockIdx.x * 256 + threadIdx.x;   // 0..32767
  float s = 0.f;
#pragma unroll 8
  for (int k = 0; k < NICT; ++k) s += partial[(size_t)k * (B_*C_*E_) + idx];
  float sq = s * s;
  sq += __shfl_xor(sq, 1); sq += __shfl_xor(sq, 2);
  sq += __shfl_xor(sq, 4); sq += __shfl_xor(sq, 8);
  float scale = sq / (1.f + sq) / (sqrtf(sq) + 1e-8f);
  float v = scale * s;
  if (mode == 0)      vacc_out[idx] = v;
  else if (mode == 1) vacc_out[idx] = vacc_in[idx] + v;
  else                vout[idx] = v;
}

extern "C" void kernel_launch(void* const* d_in, const int* in_sizes, int n_in,
                              void* d_out, int out_size, void* d_ws, size_t ws_size,
                              hipStream_t stream)
{
  const float* x = (const float*)d_in[0];
  const float* W = (const float*)d_in[1];
  float* out     = (float*)d_out;

  const int rblocks = (B_*C_*E_) / 256;   // 128

  const size_t need_big = ((size_t)(I_/4 + 1)) * (B_*C_*E_) * sizeof(float);
  if (ws_size >= need_big) {
    constexpr int ICt = 4, NIC = I_/ICt;             // 288 chunks, 37.7MB partial
    float* partial = (float*)d_ws;
    float* vacc    = partial + (size_t)NIC * (B_*C_*E_);
    dim3 pg(NIC, B_/BC_);                            // 288 x 8 = 2304 blocks
    caps_pass<ICt,false><<<pg, 256, 0, stream>>>(x, W, nullptr, partial);
    reduce_squash<NIC><<<rblocks, 256, 0, stream>>>(partial, nullptr, vacc, nullptr, 0);
    caps_pass<ICt,true ><<<pg, 256, 0, stream>>>(x, W, vacc, partial);
    reduce_squash<NIC><<<rblocks, 256, 0, stream>>>(partial, vacc, vacc, nullptr, 1);
    caps_pass<ICt,true ><<<pg, 256, 0, stream>>>(x, W, vacc, partial);
    reduce_squash<NIC><<<rblocks, 256, 0, stream>>>(partial, nullptr, nullptr, out, 2);
  } else {
    constexpr int ICt = 16, NIC = I_/ICt;            // 72 chunks, 9.4MB partial
    float* partial = (float*)d_ws;
    float* vacc    = partial + (size_t)NIC * (B_*C_*E_);
    dim3 pg(NIC, B_/BC_);                            // 72 x 8 = 576 blocks
    caps_pass<ICt,false><<<pg, 256, 0, stream>>>(x, W, nullptr, partial);
    reduce_squash<NIC><<<rblocks, 256, 0, stream>>>(partial, nullptr, vacc, nullptr, 0);
    caps_pass<ICt,true ><<<pg, 256, 0, stream>>>(x, W, vacc, partial);
    reduce_squash<NIC><<<rblocks, 256, 0, stream>>>(partial, vacc, vacc, nullptr, 1);
    caps_pass<ICt,true ><<<pg, 256, 0, stream>>>(x, W, vacc, partial);
    reduce_squash<NIC><<<rblocks, 256, 0, stream>>>(partial, nullptr, nullptr, out, 2);
  }
}

// Round 3
// 116.281 us; speedup vs baseline: 1.6916x; 1.6916x over previous
//
#include <hip/hip_runtime.h>

#define B_ 64
#define I_ 1152
#define C_ 32
#define E_ 16
#define D_ 8
#define BC_ 16               // batch rows per block (4 waves, j=4 each)
#define ICt 4                // i's per block
#define NIC (I_/ICt)         // 288 chunks
#define WROW4 (C_*D_*E_/4)   // 1024 float4 per W[i]
#define SCE (B_*C_*E_)       // 32768 s-elements

// async global->LDS DMA, 16B per lane (dest must be wave-uniform base + lane*16)
__device__ __forceinline__ void gload_lds16(const void* g, void* l) {
  typedef __attribute__((address_space(1))) const void GV;
  typedef __attribute__((address_space(3))) void LV;
  __builtin_amdgcn_global_load_lds((GV*)g, (LV*)l, 16, 0, 0);
}

// Recompute u_hat[b,i,c,e] = sum_d x[b,i,d]*W[i,c,d,e]; coupling coef (uniform
// or softmax_c of u_hat . vacc); accumulate partial s over the block's i-chunk.
// Thread map (256 thr): c=t&31, eh=(t>>5)&1 (e-half), bq=t>>6, j=0..3 ->
// b = b0 + bq*4 + j. W staged via double-buffered global_load_lds; swizzle
// (quad rotated by c-row) applied on the GLOBAL source address, LDS dest linear.
template<bool ROUTE>
__global__ __launch_bounds__(256)
void caps_pass(const float* __restrict__ x, const float* __restrict__ W,
               const float* __restrict__ vacc, float* __restrict__ partial)
{
  __shared__ float4 Wl[2][C_*32];     // 2 x 16KB W buffers
  __shared__ float4 xl[BC_*ICt*2];    // 128 float4 (2KB)

  const int t  = threadIdx.x;
  const int c  = t & 31;
  const int eh = (t >> 5) & 1;
  const int bq = t >> 6;
  const int i0 = blockIdx.x * ICt;
  const int b0 = blockIdx.y * BC_;

  // Staging map: LDS linear float4 index g = t + 256k; row cc = g>>5, slot q' = g&31 = c.
  // Want Wl[cc*32 + ((q+cc)&31)] = wg[cc*32 + q]  =>  src quad f = cc*32 + ((c - cc)&31).
  int fsrc[4];
#pragma unroll
  for (int k = 0; k < 4; ++k) {
    int cc = (t >> 5) + 8*k;
    fsrc[k] = cc*32 + ((c - cc) & 31);
  }

  const float4* wg = (const float4*)(W + (size_t)i0 * (C_*D_*E_));
  // prologue: issue W[i0] -> buf0 (async DMA)
#pragma unroll
  for (int k = 0; k < 4; ++k)
    gload_lds16(wg + fsrc[k], &Wl[0][t + 256*k]);

  // stage x for all ICt i's (128 float4)
  if (t < BC_*ICt*2) {
    int b = t >> 3, r = t & 7;                    // ICt*2 == 8
    xl[t] = ((const float4*)x)[ ((size_t)(b0 + b)*I_ + i0)*2 + r ];
  }

  float vr[4][8];
  if (ROUTE) {
#pragma unroll
    for (int j = 0; j < 4; ++j) {
      const float4* vp = (const float4*)(vacc + (((size_t)(b0 + bq*4 + j)*C_ + c)*E_ + eh*8));
      float4 a = vp[0], b = vp[1];
      vr[j][0]=a.x; vr[j][1]=a.y; vr[j][2]=a.z; vr[j][3]=a.w;
      vr[j][4]=b.x; vr[j][5]=b.y; vr[j][6]=b.z; vr[j][7]=b.w;
    }
  }

  float acc[4][8];
#pragma unroll
  for (int j = 0; j < 4; ++j)
#pragma unroll
    for (int e = 0; e < 8; ++e) acc[j][e] = 0.f;

  __syncthreads();   // drains vmcnt(0): buf0 + xl ready

  int cur = 0;
  for (int ii = 0; ii < ICt; ++ii) {
    if (ii + 1 < ICt) {                            // prefetch next W into other buffer
      const float4* wn = wg + (size_t)(ii + 1) * WROW4;
#pragma unroll
      for (int k = 0; k < 4; ++k)
        gload_lds16(wn + fsrc[k], &Wl[cur^1][t + 256*k]);
    }

    float xv[4][8];
#pragma unroll
    for (int j = 0; j < 4; ++j) {
      float4 a = xl[(bq*4 + j)*8 + ii*2 + 0];
      float4 b = xl[(bq*4 + j)*8 + ii*2 + 1];
      xv[j][0]=a.x; xv[j][1]=a.y; xv[j][2]=a.z; xv[j][3]=a.w;
      xv[j][4]=b.x; xv[j][5]=b.y; xv[j][6]=b.z; xv[j][7]=b.w;
    }

    float uh[4][8];
#pragma unroll
    for (int j = 0; j < 4; ++j)
#pragma unroll
      for (int e = 0; e < 8; ++e) uh[j][e] = 0.f;

#pragma unroll
    for (int d = 0; d < D_; ++d) {
#pragma unroll
      for (int qq = 0; qq < 2; ++qq) {
        float4 wv = Wl[cur][c*32 + (((d*4 + eh*2 + qq) + c) & 31)];
        const int eb = qq*4;
#pragma unroll
        for (int j = 0; j < 4; ++j) {
          uh[j][eb+0] = fmaf(xv[j][d], wv.x, uh[j][eb+0]);
          uh[j][eb+1] = fmaf(xv[j][d], wv.y, uh[j][eb+1]);
          uh[j][eb+2] = fmaf(xv[j][d], wv.z, uh[j][eb+2]);
          uh[j][eb+3] = fmaf(xv[j][d], wv.w, uh[j][eb+3]);
        }
      }
    }

    float coef[4];
    if (ROUTE) {
#pragma unroll
      for (int j = 0; j < 4; ++j) {
        float lg = 0.f;
#pragma unroll
        for (int e = 0; e < 8; ++e) lg = fmaf(uh[j][e], vr[j][e], lg);
        lg += __shfl_xor(lg, 32, 64);              // combine e-halves
        float m = lg;
#pragma unroll
        for (int mk = 16; mk >= 1; mk >>= 1) m = fmaxf(m, __shfl_xor(m, mk, 64));
        float p = __expf(lg - m);
        float s = p;
#pragma unroll
        for (int mk = 16; mk >= 1; mk >>= 1) s += __shfl_xor(s, mk, 64);
        coef[j] = p * __builtin_amdgcn_rcpf(s);
      }
    } else {
#pragma unroll
      for (int j = 0; j < 4; ++j) coef[j] = (1.0f / C_);
    }

#pragma unroll
    for (int j = 0; j < 4; ++j)
#pragma unroll
      for (int e = 0; e < 8; ++e) acc[j][e] = fmaf(coef[j], uh[j][e], acc[j][e]);

    __syncthreads();   // drains DMA (next buf ready) + guards buf reuse
    cur ^= 1;
  }

  // partial s for this i-chunk: [NIC][B][C][E]
#pragma unroll
  for (int j = 0; j < 4; ++j) {
    size_t base = ((size_t)blockIdx.x * B_ + (b0 + bq*4 + j)) * (C_*E_) + (size_t)c*E_ + eh*8;
    float4 o0 = {acc[j][0],acc[j][1],acc[j][2],acc[j][3]};
    float4 o1 = {acc[j][4],acc[j][5],acc[j][6],acc[j][7]};
    *(float4*)(partial + base)     = o0;
    *(float4*)(partial + base + 4) = o1;
  }
}

// stage 1: red[ko][idx] = sum of 36 i-chunks
__global__ __launch_bounds__(256)
void reduce1(const float* __restrict__ partial, float* __restrict__ red)
{
  const int idx = blockIdx.x*256 + threadIdx.x;
  const int ko  = blockIdx.y;                     // 0..7
  const float* p = partial + (size_t)(ko*36) * SCE + idx;
  float s = 0.f;
#pragma unroll 9
  for (int k = 0; k < 36; ++k) s += p[(size_t)k * SCE];
  red[(size_t)ko * SCE + idx] = s;
}

// stage 2: sum 8 split-k slabs, squash over e (16-lane groups).
// mode 0: vacc_out = v ; 1: vacc_out = vacc_in + v ; 2: vout = v
__global__ __launch_bounds__(256)
void reduce2(const float* __restrict__ red, const float* __restrict__ vacc_in,
             float* __restrict__ vacc_out, float* __restrict__ vout, int mode)
{
  const int idx = blockIdx.x*256 + threadIdx.x;
  float s = 0.f;
#pragma unroll
  for (int k = 0; k < 8; ++k) s += red[(size_t)k * SCE + idx];
  float sq = s * s;
  sq += __shfl_xor(sq, 1); sq += __shfl_xor(sq, 2);
  sq += __shfl_xor(sq, 4); sq += __shfl_xor(sq, 8);
  float scale = sq / (1.f + sq) / (sqrtf(sq) + 1e-8f);
  float v = scale * s;
  if (mode == 0)      vacc_out[idx] = v;
  else if (mode == 1) vacc_out[idx] = vacc_in[idx] + v;
  else                vout[idx] = v;
}

extern "C" void kernel_launch(void* const* d_in, const int* in_sizes, int n_in,
                              void* d_out, int out_size, void* d_ws, size_t ws_size,
                              hipStream_t stream)
{
  const float* x = (const float*)d_in[0];
  const float* W = (const float*)d_in[1];
  float* out     = (float*)d_out;

  float* partial = (float*)d_ws;                   // NIC*SCE f32 = 37.75 MB
  float* red     = partial + (size_t)NIC * SCE;    // 8*SCE f32 = 1 MB
  float* vacc    = red + 8 * SCE;                  // SCE f32 = 128 KB

  dim3 pg(NIC, B_/BC_);                            // 288 x 4 = 1152 blocks
  dim3 rg1(SCE/256, 8);                            // 128 x 8
  const int rg2 = SCE/256;                         // 128

  // iter 0: uniform coefficients (softmax of zeros = 1/32)
  caps_pass<false><<<pg, 256, 0, stream>>>(x, W, nullptr, partial);
  reduce1<<<rg1, 256, 0, stream>>>(partial, red);
  reduce2<<<rg2, 256, 0, stream>>>(red, nullptr, vacc, nullptr, 0);
  // iter 1: logits = u_hat . v0
  caps_pass<true ><<<pg, 256, 0, stream>>>(x, W, vacc, partial);
  reduce1<<<rg1, 256, 0, stream>>>(partial, red);
  reduce2<<<rg2, 256, 0, stream>>>(red, vacc, vacc, nullptr, 1);
  // iter 2: logits = u_hat . (v0+v1)
  caps_pass<true ><<<pg, 256, 0, stream>>>(x, W, vacc, partial);
  reduce1<<<rg1, 256, 0, stream>>>(partial, red);
  reduce2<<<rg2, 256, 0, stream>>>(red, nullptr, nullptr, out, 2);
}